// Round 1
// 425.060 us; speedup vs baseline: 1.0071x; 1.0071x over previous
//
#include <hip/hip_runtime.h>

typedef unsigned int u32;

// Problem shape
constexpr int B  = 2, C = 3, T = 5, H = 720, W = 1280;
constexpr int HW = H * W;
constexpr int W4 = W / 4;                  // 320 quads per row
constexpr int P4 = B * T * H * W4;         // one thread per 4 horizontal pixels = 2,304,000
constexpr int CH_STRIDE = T * HW;          // channel stride in x / f / out (fp32 elems)
constexpr int OUT_HALF  = B * C * T * HW;  // offset of second output (xw), fp32 elems
constexpr int NBLK  = P4 / 256;            // 9000 blocks (exact)
constexpr int NXCD  = 8;
constexpr int CHUNK = NBLK / NXCD;         // 1125 (9000 % 8 == 0 -> bijective swizzle)

// 8B vector load type with only 4B alignment guarantee: lets clang emit
// global_load_dwordx2 at dword-aligned addresses (legal on gfx9+ global path).
typedef float2 __attribute__((aligned(4))) f2u;

__global__ __launch_bounds__(256)
void bwarp_kernel(const float* __restrict__ x, const float* __restrict__ f,
                  float* __restrict__ out)
{
    // XCD-aware chunked swizzle: consecutive-in-image blocks stay on one XCD's L2
    // so vertically adjacent waves reuse the same x rows.
    int bid = blockIdx.x;
    int swz = (bid & (NXCD - 1)) * CHUNK + (bid >> 3);
    int i   = swz * 256 + (int)threadIdx.x;
    if (i >= P4) return;   // never taken (exact fit); keeps codegen safe

    int w4i = i % W4;
    int r   = i / W4;
    int h   = r % H;
    int bt  = r / H;           // b*T + t
    int b   = bt / T;
    int t   = bt - b * T;

    int plane = (b * 3 * T + t) * HW;          // channel-0 plane for x/f/out
    int base0 = plane + h * W + 4 * w4i;       // 16B-aligned fp32 element index

    // coalesced 16B loads of flow_x, flow_y, weight-logit quads
    float4 fx4 = *(const float4*)(f + base0);
    float4 fy4 = *(const float4*)(f + base0 + CH_STRIDE);
    float4 fw4 = *(const float4*)(f + base0 + 2 * CH_STRIDE);

    const float* fxp = (const float*)&fx4;
    const float* fyp = (const float*)&fy4;
    const float* fwp = (const float*)&fw4;

    float o0[4];
    float o1[3][4];

    #pragma unroll
    for (int j = 0; j < 4; ++j) {
        float fx = fxp[j], fy = fyp[j], fw = fwp[j];

        // align_corners=True grid algebra collapses to pixel-space offsets
        float gx = (float)(4 * w4i + j) + fx;
        float gy = (float)h + fy;

        float x0f = floorf(gx), y0f = floorf(gy);
        float wx1 = gx - x0f, wx0 = 1.0f - wx1;
        float wy1 = gy - y0f, wy0 = 1.0f - wy1;
        int x0 = (int)x0f, y0 = (int)y0f;
        int x1 = x0 + 1,   y1 = y0 + 1;

        // zeros padding: validity as multiplicative masks (branchless)
        float vx0 = (x0 >= 0 && x0 < W) ? 1.0f : 0.0f;
        float vx1 = (x1 >= 0 && x1 < W) ? 1.0f : 0.0f;
        float vy0 = (y0 >= 0 && y0 < H) ? 1.0f : 0.0f;
        float vy1 = (y1 >= 0 && y1 < H) ? 1.0f : 0.0f;

        float w00 = wx0 * wy0 * vx0 * vy0;
        float w10 = wx1 * wy0 * vx1 * vy0;
        float w01 = wx0 * wy1 * vx0 * vy1;
        float w11 = wx1 * wy1 * vx1 * vy1;

        float sigw = 1.0f / (1.0f + __expf(-fw));

        // backwarp(ones) * sigmoid(w) -- identical across channels
        o0[j] = (w00 + w10 + w01 + w11) * sigw;

        // One 8B load covers both x-corners. Invalid corners carry zero weight,
        // so only valid corners need the right value:
        //   x0 == W-1 (x1 invalid): pair is loaded at xl=W-2 -> x0 value is p.y
        //   x0 == -1  (x0 invalid): pair is loaded at xl=0   -> x1 value is p.x
        int xl  = min(max(x0, 0), W - 2);
        int y0c = min(max(y0, 0), H - 1);
        int y1c = min(max(y1, 0), H - 1);
        bool hi0 = (x0 >= W - 1);
        bool lo1 = (x0 < 0);

        int a0 = y0c * W + xl;
        int a1 = y1c * W + xl;

        #pragma unroll
        for (int c = 0; c < 3; ++c) {
            const float* xp = x + plane + c * CH_STRIDE;
            f2u p0 = *(const f2u*)(xp + a0);   // corners (x0,x1) @ row y0c
            f2u p1 = *(const f2u*)(xp + a1);   // corners (x0,x1) @ row y1c
            float v00 = hi0 ? p0.y : p0.x;
            float v10 = lo1 ? p0.x : p0.y;
            float v01 = hi0 ? p1.y : p1.x;
            float v11 = lo1 ? p1.x : p1.y;
            o1[c][j] = (w00 * v00 + w10 * v10 + w01 * v01 + w11 * v11) * sigw;
        }
    }

    float4 ow4 = make_float4(o0[0], o0[1], o0[2], o0[3]);
    #pragma unroll
    for (int c = 0; c < 3; ++c) {
        *(float4*)(out + base0 + c * CH_STRIDE) = ow4;   // ow (same per ch)
        float4 xw4 = make_float4(o1[c][0], o1[c][1], o1[c][2], o1[c][3]);
        *(float4*)(out + OUT_HALF + base0 + c * CH_STRIDE) = xw4;  // xw
    }
}

extern "C" void kernel_launch(void* const* d_in, const int* in_sizes, int n_in,
                              void* d_out, int out_size, void* d_ws, size_t ws_size,
                              hipStream_t stream) {
    const float* x = (const float*)d_in[0];
    const float* f = (const float*)d_in[1];
    float* out = (float*)d_out;
    bwarp_kernel<<<NBLK, 256, 0, stream>>>(x, f, out);
}

// Round 2
// 407.827 us; speedup vs baseline: 1.0497x; 1.0423x over previous
//
#include <hip/hip_runtime.h>

// Problem shape
constexpr int B  = 2, C = 3, T = 5, H = 720, W = 1280;
constexpr int HW = H * W;
constexpr int W4 = W / 4;                  // 320 quads per row
constexpr int P4 = B * T * H * W4;         // one thread per 4 horizontal pixels
constexpr int CH_STRIDE = T * HW;          // channel stride in x / f / out (fp32 elems)
constexpr int OUT_HALF  = B * C * T * HW;  // offset of second output (xw)
constexpr int NBLK   = P4 / 256;           // 9000 blocks (exact fit, no guard)
constexpr int ROWBLK = (H * W4) / 256;     // 900 blocks per (b,t) plane (exact)
constexpr int NXCD   = 8;
constexpr int CHUNK  = NBLK / NXCD;        // 1125 (bijective swizzle)

// 8B vector load with 4B alignment guarantee (gather addresses can be odd floats)
typedef float2 __attribute__((aligned(4))) f2u;

__global__ __launch_bounds__(256, 4)   // allow ~128 VGPRs: we WANT 24 loads in flight
void bwarp_kernel(const float* __restrict__ x, const float* __restrict__ f,
                  float* __restrict__ out)
{
    // XCD-aware chunked swizzle (kept from R1: FETCH 304->108 MB)
    int bid = blockIdx.x;
    int swz = (bid & (NXCD - 1)) * CHUNK + (bid >> 3);

    // (b,t) is block-uniform: 900 blocks per plane, blocks never straddle planes.
    // Force it scalar so gather bases live in SGPRs (1 VGPR per gather address).
    int btu = __builtin_amdgcn_readfirstlane(swz / ROWBLK);
    int i2  = (swz - btu * ROWBLK) * 256 + (int)threadIdx.x;  // index within plane
    int b   = btu / T, t = btu - b * T;
    int plane = (b * 3 * T + t) * HW;

    int w4i = i2 % W4;
    int h   = i2 / W4;
    int base0 = plane + h * W + 4 * w4i;   // 16B-aligned

    float4 fx4 = *(const float4*)(f + base0);
    float4 fy4 = *(const float4*)(f + base0 + CH_STRIDE);
    float4 fw4 = *(const float4*)(f + base0 + 2 * CH_STRIDE);
    const float* fxp = (const float*)&fx4;
    const float* fyp = (const float*)&fy4;
    const float* fwp = (const float*)&fw4;

    // ---- Phase 1: addresses + effective pair-weights for all 4 pixels ----
    // Pair-load trick: one 8B load at xl=clamp(x0,0,W-2) covers both x-corners.
    // Invalid corners have zero weight already, so the two edge cases reduce to
    // swapping the x-weights instead of selecting values per load:
    //   x0==W-1: w10==0, value of x0 is p.y  -> (wA,wB)=(w10,w00)
    //   x0==-1 : w00==0, value of x1 is p.x  -> (wA,wB)=(w10,w00)
    int   a0[4], a1[4];
    float wA[4], wB[4], wC[4], wD[4], sig[4], o0[4];

    #pragma unroll
    for (int j = 0; j < 4; ++j) {
        float gx = (float)(4 * w4i + j) + fxp[j];   // align_corners=True pixel space
        float gy = (float)h + fyp[j];

        float x0f = floorf(gx), y0f = floorf(gy);
        float wx1 = gx - x0f, wx0 = 1.0f - wx1;
        float wy1 = gy - y0f, wy0 = 1.0f - wy1;
        int x0 = (int)x0f, y0 = (int)y0f;
        int x1 = x0 + 1,   y1 = y0 + 1;

        float vx0 = (x0 >= 0 && x0 < W) ? 1.0f : 0.0f;
        float vx1 = (x1 >= 0 && x1 < W) ? 1.0f : 0.0f;
        float vy0 = (y0 >= 0 && y0 < H) ? 1.0f : 0.0f;
        float vy1 = (y1 >= 0 && y1 < H) ? 1.0f : 0.0f;

        float w00 = wx0 * wy0 * vx0 * vy0;
        float w10 = wx1 * wy0 * vx1 * vy0;
        float w01 = wx0 * wy1 * vx0 * vy1;
        float w11 = wx1 * wy1 * vx1 * vy1;

        float s = 1.0f / (1.0f + __expf(-fwp[j]));
        sig[j] = s;
        o0[j]  = (w00 + w10 + w01 + w11) * s;   // backwarp(ones)*sigmoid, all channels

        bool edge = (x0 < 0) | (x0 >= W - 1);
        wA[j] = edge ? w10 : w00;
        wB[j] = edge ? w00 : w10;
        wC[j] = edge ? w11 : w01;
        wD[j] = edge ? w01 : w11;

        int xl  = min(max(x0, 0), W - 2);
        int y0c = min(max(y0, 0), H - 1);
        int y1c = min(max(y1, 0), H - 1);
        a0[j] = y0c * W + xl;
        a1[j] = y1c * W + xl;
    }

    // ---- Phase 2: issue ALL 24 gathers before any consumption (MLP=24) ----
    f2u p0[3][4], p1[3][4];
    #pragma unroll
    for (int c = 0; c < 3; ++c) {
        const float* xp = x + plane + c * CH_STRIDE;
        #pragma unroll
        for (int j = 0; j < 4; ++j) {
            p0[c][j] = *(const f2u*)(xp + a0[j]);   // corners (x0,x1) @ row y0c
            p1[c][j] = *(const f2u*)(xp + a1[j]);   // corners (x0,x1) @ row y1c
        }
    }

    // ---- Phase 3: pure-FMA combine + coalesced float4 stores ----
    float4 ow4 = make_float4(o0[0], o0[1], o0[2], o0[3]);
    #pragma unroll
    for (int c = 0; c < 3; ++c) {
        float r[4];
        #pragma unroll
        for (int j = 0; j < 4; ++j) {
            float v = wA[j] * p0[c][j].x;
            v = fmaf(wB[j], p0[c][j].y, v);
            v = fmaf(wC[j], p1[c][j].x, v);
            v = fmaf(wD[j], p1[c][j].y, v);
            r[j] = v * sig[j];
        }
        *(float4*)(out + base0 + c * CH_STRIDE) = ow4;                       // ow
        *(float4*)(out + OUT_HALF + base0 + c * CH_STRIDE)
            = make_float4(r[0], r[1], r[2], r[3]);                           // xw
    }
}

extern "C" void kernel_launch(void* const* d_in, const int* in_sizes, int n_in,
                              void* d_out, int out_size, void* d_ws, size_t ws_size,
                              hipStream_t stream) {
    const float* x = (const float*)d_in[0];
    const float* f = (const float*)d_in[1];
    float* out = (float*)d_out;
    bwarp_kernel<<<NBLK, 256, 0, stream>>>(x, f, out);
}

// Round 3
// 380.760 us; speedup vs baseline: 1.1243x; 1.0711x over previous
//
#include <hip/hip_runtime.h>

// Problem shape
constexpr int B  = 2, C = 3, T = 5, H = 720, W = 1280;
constexpr int HW = H * W;
constexpr int CH_STRIDE = T * HW;          // channel stride in x / f / out (fp32 elems)
constexpr int OUT_HALF  = B * C * T * HW;  // offset of second output (xw)

// 2-D tiling: wave = 16 pair-cols (32 px) x 4 rows; block = 4 waves stacked = 32 px x 16 rows.
// Rationale: gather cost ~ unique 64B lines per wave-instruction. Compact 2-D wave
// footprint (128B x ~6 rows) ~15-20 lines vs ~55 for the 1-D layout.
constexpr int TILE_W = 16;                 // pair-columns per tile (32 px)
constexpr int TILE_H = 16;                 // rows per tile
constexpr int TPW = (W / 2) / TILE_W;      // 40 tiles across
constexpr int TPC = H / TILE_H;            // 45 tiles down
constexpr int TPP = TPW * TPC;             // 1800 tiles per (b,t) plane
constexpr int NBLK  = B * T * TPP;         // 18000 blocks (exact fit)
constexpr int NXCD  = 8;
constexpr int CHUNK = NBLK / NXCD;         // 2250 (bijective swizzle)

// 8B vector load with 4B alignment guarantee (gather addresses can be odd pixels)
typedef float2 __attribute__((aligned(4))) f2u;

__global__ __launch_bounds__(256, 4)
void bwarp_kernel(const float* __restrict__ x, const float* __restrict__ f,
                  float* __restrict__ out)
{
    // XCD-aware chunked swizzle (kept: FETCH 304->108 MB in R1)
    int bid = blockIdx.x;
    int swz = (bid & (NXCD - 1)) * CHUNK + (bid >> 3);

    // Block-uniform tile decomposition, scalarized
    int btu = __builtin_amdgcn_readfirstlane(swz / TPP);       // (b*T+t)
    int rem = swz - btu * TPP;
    int ty  = __builtin_amdgcn_readfirstlane(rem / TPW);
    int tx  = rem - ty * TPW;
    int b   = btu / T, t = btu - b * T;
    int plane = (b * 3 * T + t) * HW;

    // lane -> (pair-col, row) within the 32px x 16row tile
    int lx = (int)threadIdx.x & (TILE_W - 1);   // 0..15 pair-column
    int ly = (int)threadIdx.x >> 4;             // 0..15 row (wave w owns rows 4w..4w+3)
    int xpx = (tx * TILE_W + lx) * 2;           // even pixel x
    int h   = ty * TILE_H + ly;
    int base0 = plane + h * W + xpx;            // 8B-aligned fp32 index

    // coalesced 8B loads of flow_x, flow_y, weight-logit pairs
    // (each 16-lane row-group covers 128B contiguous = 2 lines; minimal)
    float2 fx2 = *(const float2*)(f + base0);
    float2 fy2 = *(const float2*)(f + base0 + CH_STRIDE);
    float2 fw2 = *(const float2*)(f + base0 + 2 * CH_STRIDE);

    // ---- Phase 1: addresses + effective pair-weights for both pixels ----
    // Pair-load trick: one 8B load at xl=clamp(x0,0,W-2) covers both x-corners.
    // Invalid corners carry zero weight, so edge cases reduce to swapping weights.
    int   a0[2], a1[2];
    float wA[2], wB[2], wC[2], wD[2], sig[2], o0[2];

    #pragma unroll
    for (int j = 0; j < 2; ++j) {
        float fx = j ? fx2.y : fx2.x;
        float fy = j ? fy2.y : fy2.x;
        float fw = j ? fw2.y : fw2.x;

        float gx = (float)(xpx + j) + fx;       // align_corners=True pixel space
        float gy = (float)h + fy;

        float x0f = floorf(gx), y0f = floorf(gy);
        float wx1 = gx - x0f, wx0 = 1.0f - wx1;
        float wy1 = gy - y0f, wy0 = 1.0f - wy1;
        int x0 = (int)x0f, y0 = (int)y0f;
        int x1 = x0 + 1,   y1 = y0 + 1;

        float vx0 = (x0 >= 0 && x0 < W) ? 1.0f : 0.0f;
        float vx1 = (x1 >= 0 && x1 < W) ? 1.0f : 0.0f;
        float vy0 = (y0 >= 0 && y0 < H) ? 1.0f : 0.0f;
        float vy1 = (y1 >= 0 && y1 < H) ? 1.0f : 0.0f;

        float w00 = wx0 * wy0 * vx0 * vy0;
        float w10 = wx1 * wy0 * vx1 * vy0;
        float w01 = wx0 * wy1 * vx0 * vy1;
        float w11 = wx1 * wy1 * vx1 * vy1;

        float s = 1.0f / (1.0f + __expf(-fw));
        sig[j] = s;
        o0[j]  = (w00 + w10 + w01 + w11) * s;

        bool edge = (x0 < 0) | (x0 >= W - 1);
        wA[j] = edge ? w10 : w00;
        wB[j] = edge ? w00 : w10;
        wC[j] = edge ? w11 : w01;
        wD[j] = edge ? w01 : w11;

        int xl  = min(max(x0, 0), W - 2);
        int y0c = min(max(y0, 0), H - 1);
        int y1c = min(max(y1, 0), H - 1);
        a0[j] = y0c * W + xl;
        a1[j] = y1c * W + xl;
    }

    // ---- Phase 2: the 12 gathers (2 px x 3 ch x 2 rows) ----
    f2u p0[3][2], p1[3][2];
    #pragma unroll
    for (int c = 0; c < 3; ++c) {
        const float* xp = x + plane + c * CH_STRIDE;
        #pragma unroll
        for (int j = 0; j < 2; ++j) {
            p0[c][j] = *(const f2u*)(xp + a0[j]);   // corners (x0,x1) @ row y0c
            p1[c][j] = *(const f2u*)(xp + a1[j]);   // corners (x0,x1) @ row y1c
        }
    }

    // ---- Phase 3: FMA combine + coalesced float2 stores ----
    float2 ow2 = make_float2(o0[0], o0[1]);
    #pragma unroll
    for (int c = 0; c < 3; ++c) {
        float r[2];
        #pragma unroll
        for (int j = 0; j < 2; ++j) {
            float v = wA[j] * p0[c][j].x;
            v = fmaf(wB[j], p0[c][j].y, v);
            v = fmaf(wC[j], p1[c][j].x, v);
            v = fmaf(wD[j], p1[c][j].y, v);
            r[j] = v * sig[j];
        }
        *(float2*)(out + base0 + c * CH_STRIDE) = ow2;                      // ow
        *(float2*)(out + OUT_HALF + base0 + c * CH_STRIDE)
            = make_float2(r[0], r[1]);                                      // xw
    }
}

extern "C" void kernel_launch(void* const* d_in, const int* in_sizes, int n_in,
                              void* d_out, int out_size, void* d_ws, size_t ws_size,
                              hipStream_t stream) {
    const float* x = (const float*)d_in[0];
    const float* f = (const float*)d_in[1];
    float* out = (float*)d_out;
    bwarp_kernel<<<NBLK, 256, 0, stream>>>(x, f, out);
}

// Round 4
// 379.286 us; speedup vs baseline: 1.1287x; 1.0039x over previous
//
#include <hip/hip_runtime.h>

typedef unsigned int u32;

// Problem shape
constexpr int B  = 2, C = 3, T = 5, H = 720, W = 1280;
constexpr int HW = H * W;
constexpr int CH_STRIDE = T * HW;          // channel stride in x / f / out (fp32 elems)
constexpr int OUT_HALF  = B * C * T * HW;  // offset of second output (xw)

// 2-D tiling: wave = 16 pair-cols (32 px) x 4 rows; block = 32 px x 16 rows.
constexpr int TILE_W = 16;                 // pair-columns per tile (32 px)
constexpr int TILE_H = 16;                 // rows per tile
constexpr int TPW = (W / 2) / TILE_W;      // 40 tiles across
constexpr int TPC = H / TILE_H;            // 45 tiles down
constexpr int TPP = TPW * TPC;             // 1800 tiles per (b,t) plane
constexpr int NBLK  = B * T * TPP;         // 18000 blocks (exact fit)
constexpr int NXCD  = 8;
constexpr int CHUNK = NBLK / NXCD;         // 2250 (bijective swizzle)

// Staged region: tile (32x16) + flow slack. Covers |fx|<~8, fy in (-6,+11] => ~6 sigma.
// Out-of-region corners (expected ~0.02 pixels per LAUNCH at N(0,1) flow) take the
// global-memory fallback path, which is exact.
constexpr int REG_W = 48;                  // px
constexpr int REG_H = 28;                  // rows
constexpr int REG_CH = REG_W * REG_H;      // 1344 floats per channel
constexpr int NF4 = 3 * REG_CH / 4;        // 1008 float4 chunks to stage

// 8B vector load with 4B alignment guarantee (fallback gather)
typedef float2 __attribute__((aligned(4))) f2u;

__global__ __launch_bounds__(256)
void bwarp_kernel(const float* __restrict__ x, const float* __restrict__ f,
                  float* __restrict__ out)
{
    __shared__ float smem[3 * REG_CH];     // 16128 B -> still 8 blocks/CU

    // XCD-aware chunked swizzle (FETCH 304->108 MB since R1)
    int bid = blockIdx.x;
    int swz = (bid & (NXCD - 1)) * CHUNK + (bid >> 3);

    // Block-uniform tile decomposition, scalarized
    int btu = __builtin_amdgcn_readfirstlane(swz / TPP);       // (b*T+t)
    int rem = swz - btu * TPP;
    int ty  = __builtin_amdgcn_readfirstlane(rem / TPW);
    int tx  = rem - ty * TPW;
    int b   = btu / T, t = btu - b * T;
    int plane = (b * 3 * T + t) * HW;

    // Region origin (always fully inside the image; edge tiles shift inward,
    // and image-clamped corners stay inside the shifted region)
    int xs = min(max(tx * TILE_W * 2 - 8, 0), W - REG_W);
    int ys = min(max(ty * TILE_H - 6, 0), H - REG_H);

    // ---- Stage region into LDS: 1008 coalesced 16B chunks, direct-to-LDS ----
    {
        int tid = (int)threadIdx.x;
        const float* src = x + plane;
        #pragma unroll
        for (int k = 0; k < 4; ++k) {
            int idx = tid + k * 256;               // float4 index
            if (idx < NF4) {
                int c   = idx / (REG_CH / 4);      // /336
                int rm  = idx - c * (REG_CH / 4);
                int ry  = rm / (REG_W / 4);        // /12
                int rx4 = rm - ry * (REG_W / 4);
                const float* gp = src + c * CH_STRIDE + (ys + ry) * W + xs + rx4 * 4;
                float* lp = smem + idx * 4;        // linear: == (c*28+ry)*48 + rx4*4
                __builtin_amdgcn_global_load_lds(
                    (const __attribute__((address_space(1))) u32*)gp,
                    (__attribute__((address_space(3))) u32*)lp, 16, 0, 0);
            }
        }
    }

    // lane -> (pair-col, row) within the 32px x 16row tile
    int lx = (int)threadIdx.x & (TILE_W - 1);   // 0..15 pair-column
    int ly = (int)threadIdx.x >> 4;             // 0..15 row
    int xpx = (tx * TILE_W + lx) * 2;           // even pixel x
    int h   = ty * TILE_H + ly;
    int base0 = plane + h * W + xpx;            // 8B-aligned fp32 index

    // coalesced 8B loads of flow_x, flow_y, weight-logit pairs (overlap the staging)
    float2 fx2 = *(const float2*)(f + base0);
    float2 fy2 = *(const float2*)(f + base0 + CH_STRIDE);
    float2 fw2 = *(const float2*)(f + base0 + 2 * CH_STRIDE);

    // ---- Phase 1: addresses + effective pair-weights for both pixels ----
    // Pair trick: one 8B read at xl=clamp(x0,0,W-2) covers both x-corners; invalid
    // corners carry zero weight, so edge cases reduce to swapping the x-weights.
    int   a0[2], a1[2], l0[2], l1[2];
    bool  inr[2];
    float wA[2], wB[2], wC[2], wD[2], sig[2], o0[2];

    #pragma unroll
    for (int j = 0; j < 2; ++j) {
        float fx = j ? fx2.y : fx2.x;
        float fy = j ? fy2.y : fy2.x;
        float fw = j ? fw2.y : fw2.x;

        float gx = (float)(xpx + j) + fx;       // align_corners=True pixel space
        float gy = (float)h + fy;

        float x0f = floorf(gx), y0f = floorf(gy);
        float wx1 = gx - x0f, wx0 = 1.0f - wx1;
        float wy1 = gy - y0f, wy0 = 1.0f - wy1;
        int x0 = (int)x0f, y0 = (int)y0f;
        int x1 = x0 + 1,   y1 = y0 + 1;

        float vx0 = (x0 >= 0 && x0 < W) ? 1.0f : 0.0f;
        float vx1 = (x1 >= 0 && x1 < W) ? 1.0f : 0.0f;
        float vy0 = (y0 >= 0 && y0 < H) ? 1.0f : 0.0f;
        float vy1 = (y1 >= 0 && y1 < H) ? 1.0f : 0.0f;

        float w00 = wx0 * wy0 * vx0 * vy0;
        float w10 = wx1 * wy0 * vx1 * vy0;
        float w01 = wx0 * wy1 * vx0 * vy1;
        float w11 = wx1 * wy1 * vx0 * vy1 * 0.0f + wx1 * wy1 * vx1 * vy1; // keep exact form below
        w11 = wx1 * wy1 * vx1 * vy1;

        float s = 1.0f / (1.0f + __expf(-fw));
        sig[j] = s;
        o0[j]  = (w00 + w10 + w01 + w11) * s;

        bool edge = (x0 < 0) | (x0 >= W - 1);
        wA[j] = edge ? w10 : w00;
        wB[j] = edge ? w00 : w10;
        wC[j] = edge ? w11 : w01;
        wD[j] = edge ? w01 : w11;

        int xl  = min(max(x0, 0), W - 2);
        int y0c = min(max(y0, 0), H - 1);
        int y1c = min(max(y1, 0), H - 1);
        a0[j] = y0c * W + xl;
        a1[j] = y1c * W + xl;

        // region-local coords; clamped copies keep the unconditional LDS reads in-bounds
        int rx  = xl - xs;
        int ry0 = y0c - ys;
        int ry1 = y1c - ys;
        inr[j] = ((u32)rx <= (u32)(REG_W - 2)) &
                 ((u32)ry0 <= (u32)(REG_H - 1)) &
                 ((u32)ry1 <= (u32)(REG_H - 1));
        int rxc = min(max(rx, 0), REG_W - 2);
        int r0c = min(max(ry0, 0), REG_H - 1);
        int r1c = min(max(ry1, 0), REG_H - 1);
        l0[j] = r0c * REG_W + rxc;
        l1[j] = r1c * REG_W + rxc;
    }

    __syncthreads();   // staging complete (compiler inserts vmcnt drain)

    // ---- Phase 2: gather from LDS (ds_read2_b32 pairs), off the VMEM pipe ----
    float v00[3][2], v10[3][2], v01[3][2], v11[3][2];
    #pragma unroll
    for (int c = 0; c < 3; ++c) {
        const float* sm = smem + c * REG_CH;
        #pragma unroll
        for (int j = 0; j < 2; ++j) {
            v00[c][j] = sm[l0[j]];
            v10[c][j] = sm[l0[j] + 1];
            v01[c][j] = sm[l1[j]];
            v11[c][j] = sm[l1[j] + 1];
        }
    }

    // rare exact fallback (expected ~0.02 lanes per launch): global gather
    #pragma unroll
    for (int j = 0; j < 2; ++j) {
        if (!inr[j]) {
            #pragma unroll
            for (int c = 0; c < 3; ++c) {
                const float* xp = x + plane + c * CH_STRIDE;
                f2u p0 = *(const f2u*)(xp + a0[j]);
                f2u p1 = *(const f2u*)(xp + a1[j]);
                v00[c][j] = p0.x; v10[c][j] = p0.y;
                v01[c][j] = p1.x; v11[c][j] = p1.y;
            }
        }
    }

    // ---- Phase 3: FMA combine + coalesced float2 stores ----
    float2 ow2 = make_float2(o0[0], o0[1]);
    #pragma unroll
    for (int c = 0; c < 3; ++c) {
        float r[2];
        #pragma unroll
        for (int j = 0; j < 2; ++j) {
            float v = wA[j] * v00[c][j];
            v = fmaf(wB[j], v10[c][j], v);
            v = fmaf(wC[j], v01[c][j], v);
            v = fmaf(wD[j], v11[c][j], v);
            r[j] = v * sig[j];
        }
        *(float2*)(out + base0 + c * CH_STRIDE) = ow2;                      // ow
        *(float2*)(out + OUT_HALF + base0 + c * CH_STRIDE)
            = make_float2(r[0], r[1]);                                      // xw
    }
}

extern "C" void kernel_launch(void* const* d_in, const int* in_sizes, int n_in,
                              void* d_out, int out_size, void* d_ws, size_t ws_size,
                              hipStream_t stream) {
    const float* x = (const float*)d_in[0];
    const float* f = (const float*)d_in[1];
    float* out = (float*)d_out;
    bwarp_kernel<<<NBLK, 256, 0, stream>>>(x, f, out);
}